// Round 15
// baseline (189.661 us; speedup 1.0000x reference)
//
#include <hip/hip_runtime.h>

#define NPTS 65536
#define MM_BLOCKS 64

// ---------------------------------------------------------------------------
// fast tanh: tanh(x) = 1 - 2/(e^{2x}+1). Saturates correctly at +-inf, no NaN.
// ---------------------------------------------------------------------------
__device__ __forceinline__ float fast_tanh(float x) {
  float e = __expf(2.0f * x);
  float r = __builtin_amdgcn_rcpf(e + 1.0f);
  return fmaf(-2.0f, r, 1.0f);
}

// ---------------------------------------------------------------------------
// DPP quad_perm lane exchange for xor masks 1/2/3 (intra-quad -- Q lives in
// lane bits 0-1).  1-op VALU swap with forwarding; no LDS pipe, no lgkmcnt
// (r11: ds_bpermute -> DPP was 149.8 -> 130.8 us).
// ---------------------------------------------------------------------------
template <int M> __device__ __forceinline__ constexpr int qpctrl() {
  return M == 1 ? 0xB1 : (M == 2 ? 0x4E : 0x1B);
}
template <int M> __device__ __forceinline__ float qperm(float x) {
  return __int_as_float(__builtin_amdgcn_mov_dpp(
      __float_as_int(x), qpctrl<M>(), 0xF, 0xF, true));
}

// ---------------------------------------------------------------------------
// FUSED 9-component jet (r12: one pass computes everything, 130.8->103.4 us).
//   v | a1,a2,a3 (dir dA) | b1,b2,b3 (dir dB=(k,+-k,0)) | t, m (t-leg)
// Legs follow standard order-3 / mixed recurrences on ONE shared tanh chain.
// t-polarization: m(+-) = psi_xt +- psi_yt.
// Buffers 9x5x2 = 90 floats; r12 measured 84 VGPR total.
// r13 lesson: do NOT convert weight loads to float4/b128 (VGPR 84->128,
// spills + bank conflicts, 103->120 us).  Scalar ds_read_b32 is free here.
// r14 lesson: never set the VGPR cap equal to natural need (cap 85 @ natural
// 84 spilled 7.7 MB); keep >=40 regs of headroom.
// ---------------------------------------------------------------------------
struct J9 {
  float v, a1, a2, a3, b1, b2, b3, t, m;
  __device__ __forceinline__ static J9 seed(float bias) {
    J9 z; z.v = bias;
    z.a1 = 0.f; z.a2 = 0.f; z.a3 = 0.f;
    z.b1 = 0.f; z.b2 = 0.f; z.b3 = 0.f;
    z.t = 0.f; z.m = 0.f;
    return z;
  }
  __device__ __forceinline__ void macc(float w, const J9& o) {
    v  = fmaf(w, o.v,  v);
    a1 = fmaf(w, o.a1, a1);
    a2 = fmaf(w, o.a2, a2);
    a3 = fmaf(w, o.a3, a3);
    b1 = fmaf(w, o.b1, b1);
    b2 = fmaf(w, o.b2, b2);
    b3 = fmaf(w, o.b3, b3);
    t  = fmaf(w, o.t,  t);
    m  = fmaf(w, o.m,  m);
  }
  __device__ __forceinline__ J9 chain() const {
    float s    = fast_tanh(v);
    float fp   = fmaf(-s, s, 1.0f);             // 1 - s^2
    float fpp  = -2.0f * s * fp;                // -2 s (1-s^2)
    float fppp = fmaf(6.0f * s, s, -2.0f) * fp; // (6 s^2 - 2)(1 - s^2)
    J9 r;
    r.v  = s;
    r.a1 = fp * a1;
    r.a2 = fmaf(fpp, a1 * a1, fp * a2);
    r.a3 = fmaf(fppp * a1, a1 * a1, fmaf(3.0f * fpp, a1 * a2, fp * a3));
    r.b1 = fp * b1;
    r.b2 = fmaf(fpp, b1 * b1, fp * b2);
    r.b3 = fmaf(fppp * b1, b1 * b1, fmaf(3.0f * fpp, b1 * b2, fp * b3));
    r.t  = fp * t;
    r.m  = fmaf(fpp, b1 * t, fp * m);
    return r;
  }
};

// whole-jet DPP exchange / butterfly-sum (hot path, masks 1/2/3 only)
template <int M> __device__ __forceinline__ J9 shflx(const J9& o) {
  J9 r;
  r.v  = qperm<M>(o.v);
  r.a1 = qperm<M>(o.a1);
  r.a2 = qperm<M>(o.a2);
  r.a3 = qperm<M>(o.a3);
  r.b1 = qperm<M>(o.b1);
  r.b2 = qperm<M>(o.b2);
  r.b3 = qperm<M>(o.b3);
  r.t  = qperm<M>(o.t);
  r.m  = qperm<M>(o.m);
  return r;
}
template <int M> __device__ __forceinline__ void redsum(J9& z) {
  z.v  += qperm<M>(z.v);
  z.a1 += qperm<M>(z.a1);
  z.a2 += qperm<M>(z.a2);
  z.a3 += qperm<M>(z.a3);
  z.b1 += qperm<M>(z.b1);
  z.b2 += qperm<M>(z.b2);
  z.b3 += qperm<M>(z.b3);
  z.t  += qperm<M>(z.t);
  z.m  += qperm<M>(z.m);
}

// ---------------------------------------------------------------------------
// Quarter-split 20->20 layer: lane owns hidden units [hb, hb+5).  Partner
// activations via DPP quad_perm, ONE recv live at a time (r8 lesson).
// W row-major [i*20+j]; 4 base pointers, all other addressing immediate.
// ---------------------------------------------------------------------------
__device__ __forceinline__ void layer20_q(const float* __restrict__ W,
                                          const float* __restrict__ bias,
                                          int hb, int hb1, int hb2, int hb3,
                                          const J9* A, J9* B) {
  const float* B0 = W + hb  * 20 + hb;
  const float* B1 = W + hb1 * 20 + hb;
  const float* B2 = W + hb2 * 20 + hb;
  const float* B3 = W + hb3 * 20 + hb;
#pragma unroll
  for (int j = 0; j < 5; ++j) B[j] = J9::seed(bias[hb + j]);
#pragma unroll
  for (int ii = 0; ii < 5; ++ii) {
    J9 s = A[ii];
#pragma unroll
    for (int j = 0; j < 5; ++j) B[j].macc(B0[ii * 20 + j], s);
    s = shflx<1>(A[ii]);
#pragma unroll
    for (int j = 0; j < 5; ++j) B[j].macc(B1[ii * 20 + j], s);
    s = shflx<2>(A[ii]);
#pragma unroll
    for (int j = 0; j < 5; ++j) B[j].macc(B2[ii * 20 + j], s);
    s = shflx<3>(A[ii]);
#pragma unroll
    for (int j = 0; j < 5; ++j) B[j].macc(B3[ii * 20 + j], s);
  }
#pragma unroll
  for (int j = 0; j < 5; ++j) B[j] = B[j].chain();
}

// LDS layout (floats, NATURAL row-major, straight copy):
// L1 W@0(9) b@9(3) | L2 W@12(60) b@72(20) | L3..L7 stride 420: W@92+420l(400)
// b@+400(20) | L8 W@2192(40) b@2232(2)
#define LDS_W_FLOATS 2234

// ---------------------------------------------------------------------------
// min/max of X[:,0] via monotone-uint keys; one partial pair per block,
// butterfly-reduced per wave inside pinn_main.
// ---------------------------------------------------------------------------
__device__ __forceinline__ unsigned flipk(float f) {
  unsigned u = __float_as_uint(f);
  return (u & 0x80000000u) ? ~u : (u | 0x80000000u);
}
__device__ __forceinline__ float unflip(unsigned k) {
  unsigned u = (k & 0x80000000u) ? (k ^ 0x80000000u) : ~k;
  return __uint_as_float(u);
}

__global__ void __launch_bounds__(256) mm_reduce(const float* __restrict__ X,
                                                 unsigned* __restrict__ mm) {
  __shared__ unsigned smin[4], smax[4];
  unsigned kmin = 0xFFFFFFFFu, kmax = 0u;
  for (int i = blockIdx.x * 256 + threadIdx.x; i < NPTS; i += gridDim.x * 256) {
    unsigned key = flipk(X[3 * i]);
    kmin = min(kmin, key);
    kmax = max(kmax, key);
  }
#pragma unroll
  for (int o = 32; o > 0; o >>= 1) {
    kmin = min(kmin, (unsigned)__shfl_down((int)kmin, o, 64));
    kmax = max(kmax, (unsigned)__shfl_down((int)kmax, o, 64));
  }
  int wv = threadIdx.x >> 6;
  if ((threadIdx.x & 63) == 0) { smin[wv] = kmin; smax[wv] = kmax; }
  __syncthreads();
  if (threadIdx.x == 0) {
    kmin = min(min(smin[0], smin[1]), min(smin[2], smin[3]));
    kmax = max(max(smax[0], smax[1]), max(smax[2], smax[3]));
    mm[2 * blockIdx.x + 0] = kmin;
    mm[2 * blockIdx.x + 1] = kmax;
  }
}

// ---------------------------------------------------------------------------
// Main kernel: SINGLE-WAVE BLOCKS (64 threads), r12 math byte-identical.
// Rationale: r12/r14 showed residency stuck at ~2 x 256-thread workgroups/CU
// regardless of VGPR (84) or launch bounds -- the limiter is workgroup
// scheduling granularity.  1-wave blocks make residency per-wave: VGPR 84
// allows 6 waves/SIMD, LDS 9216 B/block allows ~17 blocks/CU -> ~50%
// occupancy ceiling vs 28%.  Each wave stages the 8.9 KB weight set itself
// (35 L2-hit loads/lane, ~1% of the body; weights are L2-resident so no HBM
// growth).  __syncthreads is a single-wave no-op (kept for LDS dep safety).
// __launch_bounds__(64,4): VGPR cap 128, natural 84 -> 44 regs headroom
// (r14: cap==natural spills; r12: 44-headroom is proven safe).
// EIGHT LANES PER POINT: bits0-1 = hidden quarter Q, bit2 = family q.
//   q=0: dA=(k,0,0), dB=(k, k,0):  psi_x/xx/xxx, S2+/S3+, m+, p, p_x
//   q=1: dA=(0,k,0), dB=(k,-k,0):  psi_y/yy/yyy, S2-/S3-, m-, p_y
//   psi_xt = (m+ + m-)/2,  psi_yt = (m+ - m-)/2   [t-polarization]
// Copy-back mid loop mandatory (r0/r4: unrolled ping-pong = GB-scale spill).
// ---------------------------------------------------------------------------
__global__ void __launch_bounds__(64, 4) pinn_main(
    const float* __restrict__ X,
    const float* W1, const float* b1, const float* W2, const float* b2,
    const float* W3, const float* b3, const float* W4, const float* b4,
    const float* W5, const float* b5, const float* W6, const float* b6,
    const float* W7, const float* b7, const float* W8, const float* b8,
    const float* lam1p, const float* lam2p, const unsigned* __restrict__ mm,
    float* __restrict__ out) {
  __shared__ float w[LDS_W_FLOATS];
  {
    const float* Wsrc[8] = {W1, W2, W3, W4, W5, W6, W7, W8};
    const float* bsrc[8] = {b1, b2, b3, b4, b5, b6, b7, b8};
    const int nwA[8]  = {9, 60, 400, 400, 400, 400, 400, 40};
    const int nbA[8]  = {3, 20, 20, 20, 20, 20, 20, 2};
    const int offW[8] = {0, 12, 92, 512, 932, 1352, 1772, 2192};
    const int offB[8] = {9, 72, 492, 912, 1332, 1752, 2172, 2232};
#pragma unroll
    for (int a = 0; a < 8; ++a) {
      for (int s = threadIdx.x; s < nwA[a]; s += 64) w[offW[a] + s] = Wsrc[a][s];
      for (int s = threadIdx.x; s < nbA[a]; s += 64) w[offB[a] + s] = bsrc[a][s];
    }
  }

  const int lane = threadIdx.x;        // block == one wave
  const int gid  = blockIdx.x * 64 + threadIdx.x;
  const int pt   = gid >> 3;           // point index (eight lanes per point)
  const int Q    = gid & 3;            // hidden quarter
  const int q    = (gid >> 2) & 1;     // family
  const int hb   = 5 * Q;
  const int hb1  = 5 * (Q ^ 1);
  const int hb2  = 5 * (Q ^ 2);
  const int hb3  = 5 * (Q ^ 3);

  // global min/max: lane l holds block-partial l, butterfly across the wave
  unsigned pmin = mm[2 * lane + 0];
  unsigned pmax = mm[2 * lane + 1];
#pragma unroll
  for (int o = 1; o < 64; o <<= 1) {
    pmin = min(pmin, (unsigned)__shfl_xor((int)pmin, o, 64));
    pmax = max(pmax, (unsigned)__shfl_xor((int)pmax, o, 64));
  }
  float lb = unflip(pmin);
  float ub = unflip(pmax);
  float kk = 2.0f / (ub - lb);

  float x = X[3 * pt], y = X[3 * pt + 1], tt = X[3 * pt + 2];
  float h0 = fmaf(kk, x - lb, -1.0f);
  float h1 = fmaf(kk, y - lb, -1.0f);
  float h2 = fmaf(kk, tt - lb, -1.0f);

  __syncthreads();  // single-wave: compiles to a waitcnt; LDS dep safety

  // family-selected seeds (cndmask, no branch)
  float a0s = q ? 0.0f : kk, a1s = q ? kk : 0.0f;  // dA: x-dir / y-dir
  float b1s = q ? -kk : kk;                         // dB: (k,+-k,0)

  // ---- single fused network pass ----
  J9 A[5], B[5];
  {
    J9 T[3];
    {
      J9 I0 = J9::seed(0.f), I1 = J9::seed(0.f), I2 = J9::seed(0.f);
      I0.v = h0; I0.a1 = a0s; I0.b1 = kk;
      I1.v = h1; I1.a1 = a1s; I1.b1 = b1s;
      I2.v = h2; I2.t = kk;
#pragma unroll
      for (int j = 0; j < 3; ++j) {               // L1 3->3, duplicated
        J9 z = J9::seed(w[9 + j]);
        z.macc(w[0 * 3 + j], I0);
        z.macc(w[1 * 3 + j], I1);
        z.macc(w[2 * 3 + j], I2);
        T[j] = z.chain();
      }
    }
#pragma unroll
    for (int j = 0; j < 5; ++j) {                 // L2 3->20, split by quarter
      J9 z = J9::seed(w[72 + hb + j]);
#pragma unroll
      for (int i = 0; i < 3; ++i) z.macc(w[12 + i * 20 + hb + j], T[i]);
      A[j] = z.chain();
    }
  }
#pragma unroll 1
  for (int l = 0; l < 5; ++l) {                   // L3..L7, one hot body
    const float* Wl = w + 92 + l * 420;
    layer20_q(Wl, Wl + 400, hb, hb1, hb2, hb3, A, B);
#pragma unroll
    for (int jj = 0; jj < 5; ++jj) A[jj] = B[jj];
  }

  // L8 psi output: full 9-comp partial + intra-quad butterfly
  float rc1, rc2, rc3, s2, s3, rm;
  {
    J9 z = J9::seed(0.f);
#pragma unroll
    for (int ii = 0; ii < 5; ++ii) z.macc(w[2192 + (hb + ii) * 2 + 0], A[ii]);
    redsum<1>(z); redsum<2>(z);
    z.v += w[2232];
    J9 o = z.chain();
    rc1 = o.a1; rc2 = o.a2; rc3 = o.a3;
    s2 = o.b2; s3 = o.b3; rm = o.m;
  }
  // L8 p output: only {v, a1} needed -> 2-float partial
  float rpv, rpc;
  {
    float pv = 0.f, pa = 0.f;
#pragma unroll
    for (int ii = 0; ii < 5; ++ii) {
      float wt = w[2192 + (hb + ii) * 2 + 1];
      pv = fmaf(wt, A[ii].v,  pv);
      pa = fmaf(wt, A[ii].a1, pa);
    }
    pv += qperm<1>(pv); pa += qperm<1>(pa);
    pv += qperm<2>(pv); pa += qperm<2>(pa);
    pv += w[2233];
    float s = fast_tanh(pv);
    rpv = s;
    rpc = fmaf(-s, s, 1.0f) * pa;
  }

  // cross-family exchange (mask 4 -- crosses quads, keep __shfl_xor; cold)
  float psi_y   = __shfl_xor(rc1, 4, 64);
  float psi_yy  = __shfl_xor(rc2, 4, 64);
  float psi_yyy = __shfl_xor(rc3, 4, 64);
  float p_y     = __shfl_xor(rpc, 4, 64);
  float S2m     = __shfl_xor(s2, 4, 64);
  float S3m     = __shfl_xor(s3, 4, 64);
  float mB      = __shfl_xor(rm, 4, 64);   // m- (on q=0 lanes)

  if ((gid & 7) == 0) {
    float psi_x = rc1, psi_xx = rc2, psi_xxx = rc3;
    float p_val = rpv, p_x = rpc;
    float S2p = s2, S3p = s3;

    // polarization identities (spatial + t-polarization)
    float psi_xy  = 0.25f * (S2p - S2m);
    float psi_xxy = (S3p - S3m - 2.0f * psi_yyy) * (1.0f / 6.0f);
    float psi_xyy = (S3p + S3m - 2.0f * psi_xxx) * (1.0f / 6.0f);
    float psi_xt  = 0.5f * (rm + mB);
    float psi_yt  = 0.5f * (rm - mB);

    float u = psi_y, vv = -psi_x;
    float u_x = psi_xy,  u_y = psi_yy,  u_t = psi_yt;
    float v_x = -psi_xx, v_y = -psi_xy, v_t = -psi_xt;
    float u_xx = psi_xxy,  u_yy = psi_yyy;
    float v_xx = -psi_xxx, v_yy = -psi_xyy;

    float lam1 = lam1p[0], lam2 = lam2p[0];
    float f_u = u_t + lam1 * (u * u_x + vv * u_y) + p_x - lam2 * (u_xx + u_yy);
    float f_v = v_t + lam1 * (u * v_x + vv * v_y) + p_y - lam2 * (v_xx + v_yy);

    out[pt] = u;
    out[NPTS + pt] = vv;
    out[2 * NPTS + pt] = p_val;
    out[3 * NPTS + pt] = f_u;
    out[4 * NPTS + pt] = f_v;
  }
}

extern "C" void kernel_launch(void* const* d_in, const int* in_sizes, int n_in,
                              void* d_out, int out_size, void* d_ws, size_t ws_size,
                              hipStream_t stream) {
  (void)in_sizes; (void)n_in; (void)out_size; (void)ws_size;
  const float* X = (const float*)d_in[0];
  const float* W[8]; const float* B[8];
  for (int i = 0; i < 8; ++i) {
    W[i] = (const float*)d_in[1 + 2 * i];
    B[i] = (const float*)d_in[2 + 2 * i];
  }
  const float* lam1 = (const float*)d_in[17];
  const float* lam2 = (const float*)d_in[18];
  unsigned* mm = (unsigned*)d_ws;
  float* out = (float*)d_out;

  hipLaunchKernelGGL(mm_reduce, dim3(MM_BLOCKS), dim3(256), 0, stream, X, mm);
  hipLaunchKernelGGL(pinn_main, dim3(8 * NPTS / 64), dim3(64), 0, stream,
                     X, W[0], B[0], W[1], B[1], W[2], B[2], W[3], B[3],
                     W[4], B[4], W[5], B[5], W[6], B[6], W[7], B[7],
                     lam1, lam2, mm, out);
}

// Round 16
// 187.298 us; speedup vs baseline: 1.0126x; 1.0126x over previous
//
#include <hip/hip_runtime.h>

#define NPTS 65536
#define MM_BLOCKS 64

// ---------------------------------------------------------------------------
// fast tanh: tanh(x) = 1 - 2/(e^{2x}+1). Saturates correctly at +-inf, no NaN.
// ---------------------------------------------------------------------------
__device__ __forceinline__ float fast_tanh(float x) {
  float e = __expf(2.0f * x);
  float r = __builtin_amdgcn_rcpf(e + 1.0f);
  return fmaf(-2.0f, r, 1.0f);
}

// ---------------------------------------------------------------------------
// DPP quad_perm lane exchange for xor masks 1/2/3 (intra-quad -- Q lives in
// lane bits 0-1).  1-op VALU swap with forwarding; no LDS pipe, no lgkmcnt
// (r11: ds_bpermute -> DPP was 149.8 -> 130.8 us).
// ---------------------------------------------------------------------------
template <int M> __device__ __forceinline__ constexpr int qpctrl() {
  return M == 1 ? 0xB1 : (M == 2 ? 0x4E : 0x1B);
}
template <int M> __device__ __forceinline__ float qperm(float x) {
  return __int_as_float(__builtin_amdgcn_mov_dpp(
      __float_as_int(x), qpctrl<M>(), 0xF, 0xF, true));
}

// ---------------------------------------------------------------------------
// FUSED 9-component jet (r12: one pass computes everything, 130.8->103.4 us).
//   v | a1,a2,a3 (dir dA) | b1,b2,b3 (dir dB=(k,+-k,0)) | t, m (t-leg)
// Legs follow standard order-3 / mixed recurrences on ONE shared tanh chain.
// t-polarization: m(+-) = psi_xt +- psi_yt.
// Buffers 9x5x2 = 90 floats; natural allocation 84 VGPR (r12 measured).
// r13: no float4/b128 weight loads (VGPR 84->128, spills, 103->120 us).
// r14: never set a VGPR cap equal to natural need (cap 85 spilled 7.7 MB).
// r15: (64,4) squeezed cap to 64 < natural 84 -> 15 MB spill, 113 us.
// => NO second launch_bounds argument, period.
// ---------------------------------------------------------------------------
struct J9 {
  float v, a1, a2, a3, b1, b2, b3, t, m;
  __device__ __forceinline__ static J9 seed(float bias) {
    J9 z; z.v = bias;
    z.a1 = 0.f; z.a2 = 0.f; z.a3 = 0.f;
    z.b1 = 0.f; z.b2 = 0.f; z.b3 = 0.f;
    z.t = 0.f; z.m = 0.f;
    return z;
  }
  __device__ __forceinline__ void macc(float w, const J9& o) {
    v  = fmaf(w, o.v,  v);
    a1 = fmaf(w, o.a1, a1);
    a2 = fmaf(w, o.a2, a2);
    a3 = fmaf(w, o.a3, a3);
    b1 = fmaf(w, o.b1, b1);
    b2 = fmaf(w, o.b2, b2);
    b3 = fmaf(w, o.b3, b3);
    t  = fmaf(w, o.t,  t);
    m  = fmaf(w, o.m,  m);
  }
  __device__ __forceinline__ J9 chain() const {
    float s    = fast_tanh(v);
    float fp   = fmaf(-s, s, 1.0f);             // 1 - s^2
    float fpp  = -2.0f * s * fp;                // -2 s (1-s^2)
    float fppp = fmaf(6.0f * s, s, -2.0f) * fp; // (6 s^2 - 2)(1 - s^2)
    J9 r;
    r.v  = s;
    r.a1 = fp * a1;
    r.a2 = fmaf(fpp, a1 * a1, fp * a2);
    r.a3 = fmaf(fppp * a1, a1 * a1, fmaf(3.0f * fpp, a1 * a2, fp * a3));
    r.b1 = fp * b1;
    r.b2 = fmaf(fpp, b1 * b1, fp * b2);
    r.b3 = fmaf(fppp * b1, b1 * b1, fmaf(3.0f * fpp, b1 * b2, fp * b3));
    r.t  = fp * t;
    r.m  = fmaf(fpp, b1 * t, fp * m);
    return r;
  }
};

// whole-jet DPP exchange / butterfly-sum (hot path, masks 1/2/3 only)
template <int M> __device__ __forceinline__ J9 shflx(const J9& o) {
  J9 r;
  r.v  = qperm<M>(o.v);
  r.a1 = qperm<M>(o.a1);
  r.a2 = qperm<M>(o.a2);
  r.a3 = qperm<M>(o.a3);
  r.b1 = qperm<M>(o.b1);
  r.b2 = qperm<M>(o.b2);
  r.b3 = qperm<M>(o.b3);
  r.t  = qperm<M>(o.t);
  r.m  = qperm<M>(o.m);
  return r;
}
template <int M> __device__ __forceinline__ void redsum(J9& z) {
  z.v  += qperm<M>(z.v);
  z.a1 += qperm<M>(z.a1);
  z.a2 += qperm<M>(z.a2);
  z.a3 += qperm<M>(z.a3);
  z.b1 += qperm<M>(z.b1);
  z.b2 += qperm<M>(z.b2);
  z.b3 += qperm<M>(z.b3);
  z.t  += qperm<M>(z.t);
  z.m  += qperm<M>(z.m);
}

// ---------------------------------------------------------------------------
// Quarter-split 20->20 layer: lane owns hidden units [hb, hb+5).  Partner
// activations via DPP quad_perm, ONE recv live at a time (r8 lesson).
// W row-major [i*20+j]; 4 base pointers, all other addressing immediate.
// ---------------------------------------------------------------------------
__device__ __forceinline__ void layer20_q(const float* __restrict__ W,
                                          const float* __restrict__ bias,
                                          int hb, int hb1, int hb2, int hb3,
                                          const J9* A, J9* B) {
  const float* B0 = W + hb  * 20 + hb;
  const float* B1 = W + hb1 * 20 + hb;
  const float* B2 = W + hb2 * 20 + hb;
  const float* B3 = W + hb3 * 20 + hb;
#pragma unroll
  for (int j = 0; j < 5; ++j) B[j] = J9::seed(bias[hb + j]);
#pragma unroll
  for (int ii = 0; ii < 5; ++ii) {
    J9 s = A[ii];
#pragma unroll
    for (int j = 0; j < 5; ++j) B[j].macc(B0[ii * 20 + j], s);
    s = shflx<1>(A[ii]);
#pragma unroll
    for (int j = 0; j < 5; ++j) B[j].macc(B1[ii * 20 + j], s);
    s = shflx<2>(A[ii]);
#pragma unroll
    for (int j = 0; j < 5; ++j) B[j].macc(B2[ii * 20 + j], s);
    s = shflx<3>(A[ii]);
#pragma unroll
    for (int j = 0; j < 5; ++j) B[j].macc(B3[ii * 20 + j], s);
  }
#pragma unroll
  for (int j = 0; j < 5; ++j) B[j] = B[j].chain();
}

// LDS layout (floats, NATURAL row-major, straight copy):
// L1 W@0(9) b@9(3) | L2 W@12(60) b@72(20) | L3..L7 stride 420: W@92+420l(400)
// b@+400(20) | L8 W@2192(40) b@2232(2)
#define LDS_W_FLOATS 2234

// ---------------------------------------------------------------------------
// min/max of X[:,0] via monotone-uint keys; one partial pair per block,
// butterfly-reduced per wave inside pinn_main.
// ---------------------------------------------------------------------------
__device__ __forceinline__ unsigned flipk(float f) {
  unsigned u = __float_as_uint(f);
  return (u & 0x80000000u) ? ~u : (u | 0x80000000u);
}
__device__ __forceinline__ float unflip(unsigned k) {
  unsigned u = (k & 0x80000000u) ? (k ^ 0x80000000u) : ~k;
  return __uint_as_float(u);
}

__global__ void __launch_bounds__(256) mm_reduce(const float* __restrict__ X,
                                                 unsigned* __restrict__ mm) {
  __shared__ unsigned smin[4], smax[4];
  unsigned kmin = 0xFFFFFFFFu, kmax = 0u;
  for (int i = blockIdx.x * 256 + threadIdx.x; i < NPTS; i += gridDim.x * 256) {
    unsigned key = flipk(X[3 * i]);
    kmin = min(kmin, key);
    kmax = max(kmax, key);
  }
#pragma unroll
  for (int o = 32; o > 0; o >>= 1) {
    kmin = min(kmin, (unsigned)__shfl_down((int)kmin, o, 64));
    kmax = max(kmax, (unsigned)__shfl_down((int)kmax, o, 64));
  }
  int wv = threadIdx.x >> 6;
  if ((threadIdx.x & 63) == 0) { smin[wv] = kmin; smax[wv] = kmax; }
  __syncthreads();
  if (threadIdx.x == 0) {
    kmin = min(min(smin[0], smin[1]), min(smin[2], smin[3]));
    kmax = max(max(smax[0], smax[1]), max(smax[2], smax[3]));
    mm[2 * blockIdx.x + 0] = kmin;
    mm[2 * blockIdx.x + 1] = kmax;
  }
}

// ---------------------------------------------------------------------------
// Main kernel: SINGLE-WAVE BLOCKS (64 threads), r12 math byte-identical,
// PLAIN __launch_bounds__(64) -- the r15 retry decontaminated.
// r15 evidence: 1-wave blocks DID raise occupancy 28->36% (workgroup
// granularity was a real limiter) but (64,4) squeezed VGPR to 64 < natural
// 84 -> 15 MB spill -> 113 us.  Plain bounds has produced natural allocation
// in every prior case (r5: 252, r12: 84); expected here: 84 VGPR, zero
// spill, occupancy >= 36%.
// EIGHT LANES PER POINT: bits0-1 = hidden quarter Q, bit2 = family q.
//   q=0: dA=(k,0,0), dB=(k, k,0):  psi_x/xx/xxx, S2+/S3+, m+, p, p_x
//   q=1: dA=(0,k,0), dB=(k,-k,0):  psi_y/yy/yyy, S2-/S3-, m-, p_y
//   psi_xt = (m+ + m-)/2,  psi_yt = (m+ - m-)/2   [t-polarization]
// Copy-back mid loop mandatory (r0/r4: unrolled ping-pong = GB-scale spill).
// ---------------------------------------------------------------------------
__global__ void __launch_bounds__(64) pinn_main(
    const float* __restrict__ X,
    const float* W1, const float* b1, const float* W2, const float* b2,
    const float* W3, const float* b3, const float* W4, const float* b4,
    const float* W5, const float* b5, const float* W6, const float* b6,
    const float* W7, const float* b7, const float* W8, const float* b8,
    const float* lam1p, const float* lam2p, const unsigned* __restrict__ mm,
    float* __restrict__ out) {
  __shared__ float w[LDS_W_FLOATS];
  {
    const float* Wsrc[8] = {W1, W2, W3, W4, W5, W6, W7, W8};
    const float* bsrc[8] = {b1, b2, b3, b4, b5, b6, b7, b8};
    const int nwA[8]  = {9, 60, 400, 400, 400, 400, 400, 40};
    const int nbA[8]  = {3, 20, 20, 20, 20, 20, 20, 2};
    const int offW[8] = {0, 12, 92, 512, 932, 1352, 1772, 2192};
    const int offB[8] = {9, 72, 492, 912, 1332, 1752, 2172, 2232};
#pragma unroll
    for (int a = 0; a < 8; ++a) {
      for (int s = threadIdx.x; s < nwA[a]; s += 64) w[offW[a] + s] = Wsrc[a][s];
      for (int s = threadIdx.x; s < nbA[a]; s += 64) w[offB[a] + s] = bsrc[a][s];
    }
  }

  const int lane = threadIdx.x;        // block == one wave
  const int gid  = blockIdx.x * 64 + threadIdx.x;
  const int pt   = gid >> 3;           // point index (eight lanes per point)
  const int Q    = gid & 3;            // hidden quarter
  const int q    = (gid >> 2) & 1;     // family
  const int hb   = 5 * Q;
  const int hb1  = 5 * (Q ^ 1);
  const int hb2  = 5 * (Q ^ 2);
  const int hb3  = 5 * (Q ^ 3);

  // global min/max: lane l holds block-partial l, butterfly across the wave
  unsigned pmin = mm[2 * lane + 0];
  unsigned pmax = mm[2 * lane + 1];
#pragma unroll
  for (int o = 1; o < 64; o <<= 1) {
    pmin = min(pmin, (unsigned)__shfl_xor((int)pmin, o, 64));
    pmax = max(pmax, (unsigned)__shfl_xor((int)pmax, o, 64));
  }
  float lb = unflip(pmin);
  float ub = unflip(pmax);
  float kk = 2.0f / (ub - lb);

  float x = X[3 * pt], y = X[3 * pt + 1], tt = X[3 * pt + 2];
  float h0 = fmaf(kk, x - lb, -1.0f);
  float h1 = fmaf(kk, y - lb, -1.0f);
  float h2 = fmaf(kk, tt - lb, -1.0f);

  __syncthreads();  // single-wave: compiles to a waitcnt; LDS dep safety

  // family-selected seeds (cndmask, no branch)
  float a0s = q ? 0.0f : kk, a1s = q ? kk : 0.0f;  // dA: x-dir / y-dir
  float b1s = q ? -kk : kk;                         // dB: (k,+-k,0)

  // ---- single fused network pass ----
  J9 A[5], B[5];
  {
    J9 T[3];
    {
      J9 I0 = J9::seed(0.f), I1 = J9::seed(0.f), I2 = J9::seed(0.f);
      I0.v = h0; I0.a1 = a0s; I0.b1 = kk;
      I1.v = h1; I1.a1 = a1s; I1.b1 = b1s;
      I2.v = h2; I2.t = kk;
#pragma unroll
      for (int j = 0; j < 3; ++j) {               // L1 3->3, duplicated
        J9 z = J9::seed(w[9 + j]);
        z.macc(w[0 * 3 + j], I0);
        z.macc(w[1 * 3 + j], I1);
        z.macc(w[2 * 3 + j], I2);
        T[j] = z.chain();
      }
    }
#pragma unroll
    for (int j = 0; j < 5; ++j) {                 // L2 3->20, split by quarter
      J9 z = J9::seed(w[72 + hb + j]);
#pragma unroll
      for (int i = 0; i < 3; ++i) z.macc(w[12 + i * 20 + hb + j], T[i]);
      A[j] = z.chain();
    }
  }
#pragma unroll 1
  for (int l = 0; l < 5; ++l) {                   // L3..L7, one hot body
    const float* Wl = w + 92 + l * 420;
    layer20_q(Wl, Wl + 400, hb, hb1, hb2, hb3, A, B);
#pragma unroll
    for (int jj = 0; jj < 5; ++jj) A[jj] = B[jj];
  }

  // L8 psi output: full 9-comp partial + intra-quad butterfly
  float rc1, rc2, rc3, s2, s3, rm;
  {
    J9 z = J9::seed(0.f);
#pragma unroll
    for (int ii = 0; ii < 5; ++ii) z.macc(w[2192 + (hb + ii) * 2 + 0], A[ii]);
    redsum<1>(z); redsum<2>(z);
    z.v += w[2232];
    J9 o = z.chain();
    rc1 = o.a1; rc2 = o.a2; rc3 = o.a3;
    s2 = o.b2; s3 = o.b3; rm = o.m;
  }
  // L8 p output: only {v, a1} needed -> 2-float partial
  float rpv, rpc;
  {
    float pv = 0.f, pa = 0.f;
#pragma unroll
    for (int ii = 0; ii < 5; ++ii) {
      float wt = w[2192 + (hb + ii) * 2 + 1];
      pv = fmaf(wt, A[ii].v,  pv);
      pa = fmaf(wt, A[ii].a1, pa);
    }
    pv += qperm<1>(pv); pa += qperm<1>(pa);
    pv += qperm<2>(pv); pa += qperm<2>(pa);
    pv += w[2233];
    float s = fast_tanh(pv);
    rpv = s;
    rpc = fmaf(-s, s, 1.0f) * pa;
  }

  // cross-family exchange (mask 4 -- crosses quads, keep __shfl_xor; cold)
  float psi_y   = __shfl_xor(rc1, 4, 64);
  float psi_yy  = __shfl_xor(rc2, 4, 64);
  float psi_yyy = __shfl_xor(rc3, 4, 64);
  float p_y     = __shfl_xor(rpc, 4, 64);
  float S2m     = __shfl_xor(s2, 4, 64);
  float S3m     = __shfl_xor(s3, 4, 64);
  float mB      = __shfl_xor(rm, 4, 64);   // m- (on q=0 lanes)

  if ((gid & 7) == 0) {
    float psi_x = rc1, psi_xx = rc2, psi_xxx = rc3;
    float p_val = rpv, p_x = rpc;
    float S2p = s2, S3p = s3;

    // polarization identities (spatial + t-polarization)
    float psi_xy  = 0.25f * (S2p - S2m);
    float psi_xxy = (S3p - S3m - 2.0f * psi_yyy) * (1.0f / 6.0f);
    float psi_xyy = (S3p + S3m - 2.0f * psi_xxx) * (1.0f / 6.0f);
    float psi_xt  = 0.5f * (rm + mB);
    float psi_yt  = 0.5f * (rm - mB);

    float u = psi_y, vv = -psi_x;
    float u_x = psi_xy,  u_y = psi_yy,  u_t = psi_yt;
    float v_x = -psi_xx, v_y = -psi_xy, v_t = -psi_xt;
    float u_xx = psi_xxy,  u_yy = psi_yyy;
    float v_xx = -psi_xxx, v_yy = -psi_xyy;

    float lam1 = lam1p[0], lam2 = lam2p[0];
    float f_u = u_t + lam1 * (u * u_x + vv * u_y) + p_x - lam2 * (u_xx + u_yy);
    float f_v = v_t + lam1 * (u * v_x + vv * v_y) + p_y - lam2 * (v_xx + v_yy);

    out[pt] = u;
    out[NPTS + pt] = vv;
    out[2 * NPTS + pt] = p_val;
    out[3 * NPTS + pt] = f_u;
    out[4 * NPTS + pt] = f_v;
  }
}

extern "C" void kernel_launch(void* const* d_in, const int* in_sizes, int n_in,
                              void* d_out, int out_size, void* d_ws, size_t ws_size,
                              hipStream_t stream) {
  (void)in_sizes; (void)n_in; (void)out_size; (void)ws_size;
  const float* X = (const float*)d_in[0];
  const float* W[8]; const float* B[8];
  for (int i = 0; i < 8; ++i) {
    W[i] = (const float*)d_in[1 + 2 * i];
    B[i] = (const float*)d_in[2 + 2 * i];
  }
  const float* lam1 = (const float*)d_in[17];
  const float* lam2 = (const float*)d_in[18];
  unsigned* mm = (unsigned*)d_ws;
  float* out = (float*)d_out;

  hipLaunchKernelGGL(mm_reduce, dim3(MM_BLOCKS), dim3(256), 0, stream, X, mm);
  hipLaunchKernelGGL(pinn_main, dim3(8 * NPTS / 64), dim3(64), 0, stream,
                     X, W[0], B[0], W[1], B[1], W[2], B[2], W[3], B[3],
                     W[4], B[4], W[5], B[5], W[6], B[6], W[7], B[7],
                     lam1, lam2, mm, out);
}

// Round 17
// 181.159 us; speedup vs baseline: 1.0469x; 1.0339x over previous
//
#include <hip/hip_runtime.h>

#define NPTS 65536
#define MM_BLOCKS 64

// ---------------------------------------------------------------------------
// fast tanh: tanh(x) = 1 - 2/(e^{2x}+1). Saturates correctly at +-inf, no NaN.
// ---------------------------------------------------------------------------
__device__ __forceinline__ float fast_tanh(float x) {
  float e = __expf(2.0f * x);
  float r = __builtin_amdgcn_rcpf(e + 1.0f);
  return fmaf(-2.0f, r, 1.0f);
}

// ---------------------------------------------------------------------------
// DPP quad_perm lane exchange for xor masks 1/2/3 (intra-quad -- Q lives in
// lane bits 0-1).  1-op VALU swap with forwarding; no LDS pipe, no lgkmcnt
// (r11: ds_bpermute -> DPP was 149.8 -> 130.8 us).
// ---------------------------------------------------------------------------
template <int M> __device__ __forceinline__ constexpr int qpctrl() {
  return M == 1 ? 0xB1 : (M == 2 ? 0x4E : 0x1B);
}
template <int M> __device__ __forceinline__ float qperm(float x) {
  return __int_as_float(__builtin_amdgcn_mov_dpp(
      __float_as_int(x), qpctrl<M>(), 0xF, 0xF, true));
}

// ---------------------------------------------------------------------------
// FUSED 9-component jet (r12: one pass computes everything, 130.8->103.4 us).
//   v | a1,a2,a3 (dir dA) | b1,b2,b3 (dir dB=(k,+-k,0)) | t, m (t-leg)
// Legs follow standard order-3 / mixed recurrences on ONE shared tanh chain.
// t-polarization: m(+-) = psi_xt +- psi_yt.
// Buffers 9x5x2 = 90 floats; natural allocation 84 VGPR (r12 measured).
// SETTLED LESSONS (do not revisit):
//   r13: float4/b128 weight loads -> VGPR 84->128, spills, 120 us.  Scalar
//        ds_read_b32 weight loads are effectively free on the critical path.
//   r14: VGPR cap == natural need (256,3 -> cap 85) -> 7.7 MB spill, 113 us.
//   r15: (64,4) -> cap 64 < natural 84 -> 15 MB spill, 113 us.
//   r16: single-wave blocks, clean alloc -> occupancy ceiling is ~30%
//        REGARDLESS of block size; per-wave staging costs ~14 us -> 117 us.
//   => (256,2) with 44 regs of cap headroom is the measured optimum.
// ---------------------------------------------------------------------------
struct J9 {
  float v, a1, a2, a3, b1, b2, b3, t, m;
  __device__ __forceinline__ static J9 seed(float bias) {
    J9 z; z.v = bias;
    z.a1 = 0.f; z.a2 = 0.f; z.a3 = 0.f;
    z.b1 = 0.f; z.b2 = 0.f; z.b3 = 0.f;
    z.t = 0.f; z.m = 0.f;
    return z;
  }
  __device__ __forceinline__ void macc(float w, const J9& o) {
    v  = fmaf(w, o.v,  v);
    a1 = fmaf(w, o.a1, a1);
    a2 = fmaf(w, o.a2, a2);
    a3 = fmaf(w, o.a3, a3);
    b1 = fmaf(w, o.b1, b1);
    b2 = fmaf(w, o.b2, b2);
    b3 = fmaf(w, o.b3, b3);
    t  = fmaf(w, o.t,  t);
    m  = fmaf(w, o.m,  m);
  }
  __device__ __forceinline__ J9 chain() const {
    float s    = fast_tanh(v);
    float fp   = fmaf(-s, s, 1.0f);             // 1 - s^2
    float fpp  = -2.0f * s * fp;                // -2 s (1-s^2)
    float fppp = fmaf(6.0f * s, s, -2.0f) * fp; // (6 s^2 - 2)(1 - s^2)
    J9 r;
    r.v  = s;
    r.a1 = fp * a1;
    r.a2 = fmaf(fpp, a1 * a1, fp * a2);
    r.a3 = fmaf(fppp * a1, a1 * a1, fmaf(3.0f * fpp, a1 * a2, fp * a3));
    r.b1 = fp * b1;
    r.b2 = fmaf(fpp, b1 * b1, fp * b2);
    r.b3 = fmaf(fppp * b1, b1 * b1, fmaf(3.0f * fpp, b1 * b2, fp * b3));
    r.t  = fp * t;
    r.m  = fmaf(fpp, b1 * t, fp * m);
    return r;
  }
};

// whole-jet DPP exchange / butterfly-sum (hot path, masks 1/2/3 only)
template <int M> __device__ __forceinline__ J9 shflx(const J9& o) {
  J9 r;
  r.v  = qperm<M>(o.v);
  r.a1 = qperm<M>(o.a1);
  r.a2 = qperm<M>(o.a2);
  r.a3 = qperm<M>(o.a3);
  r.b1 = qperm<M>(o.b1);
  r.b2 = qperm<M>(o.b2);
  r.b3 = qperm<M>(o.b3);
  r.t  = qperm<M>(o.t);
  r.m  = qperm<M>(o.m);
  return r;
}
template <int M> __device__ __forceinline__ void redsum(J9& z) {
  z.v  += qperm<M>(z.v);
  z.a1 += qperm<M>(z.a1);
  z.a2 += qperm<M>(z.a2);
  z.a3 += qperm<M>(z.a3);
  z.b1 += qperm<M>(z.b1);
  z.b2 += qperm<M>(z.b2);
  z.b3 += qperm<M>(z.b3);
  z.t  += qperm<M>(z.t);
  z.m  += qperm<M>(z.m);
}

// ---------------------------------------------------------------------------
// Quarter-split 20->20 layer: lane owns hidden units [hb, hb+5).  Partner
// activations via DPP quad_perm, ONE recv live at a time (r8 lesson).
// W row-major [i*20+j]; 4 base pointers, all other addressing immediate.
// ---------------------------------------------------------------------------
__device__ __forceinline__ void layer20_q(const float* __restrict__ W,
                                          const float* __restrict__ bias,
                                          int hb, int hb1, int hb2, int hb3,
                                          const J9* A, J9* B) {
  const float* B0 = W + hb  * 20 + hb;
  const float* B1 = W + hb1 * 20 + hb;
  const float* B2 = W + hb2 * 20 + hb;
  const float* B3 = W + hb3 * 20 + hb;
#pragma unroll
  for (int j = 0; j < 5; ++j) B[j] = J9::seed(bias[hb + j]);
#pragma unroll
  for (int ii = 0; ii < 5; ++ii) {
    J9 s = A[ii];
#pragma unroll
    for (int j = 0; j < 5; ++j) B[j].macc(B0[ii * 20 + j], s);
    s = shflx<1>(A[ii]);
#pragma unroll
    for (int j = 0; j < 5; ++j) B[j].macc(B1[ii * 20 + j], s);
    s = shflx<2>(A[ii]);
#pragma unroll
    for (int j = 0; j < 5; ++j) B[j].macc(B2[ii * 20 + j], s);
    s = shflx<3>(A[ii]);
#pragma unroll
    for (int j = 0; j < 5; ++j) B[j].macc(B3[ii * 20 + j], s);
  }
#pragma unroll
  for (int j = 0; j < 5; ++j) B[j] = B[j].chain();
}

// LDS layout (floats, NATURAL row-major, straight copy):
// L1 W@0(9) b@9(3) | L2 W@12(60) b@72(20) | L3..L7 stride 420: W@92+420l(400)
// b@+400(20) | L8 W@2192(40) b@2232(2)
#define LDS_W_FLOATS 2234

// ---------------------------------------------------------------------------
// min/max of X[:,0] via monotone-uint keys; one partial pair per block,
// butterfly-reduced per wave inside pinn_main.
// ---------------------------------------------------------------------------
__device__ __forceinline__ unsigned flipk(float f) {
  unsigned u = __float_as_uint(f);
  return (u & 0x80000000u) ? ~u : (u | 0x80000000u);
}
__device__ __forceinline__ float unflip(unsigned k) {
  unsigned u = (k & 0x80000000u) ? (k ^ 0x80000000u) : ~k;
  return __uint_as_float(u);
}

__global__ void __launch_bounds__(256) mm_reduce(const float* __restrict__ X,
                                                 unsigned* __restrict__ mm) {
  __shared__ unsigned smin[4], smax[4];
  unsigned kmin = 0xFFFFFFFFu, kmax = 0u;
  for (int i = blockIdx.x * 256 + threadIdx.x; i < NPTS; i += gridDim.x * 256) {
    unsigned key = flipk(X[3 * i]);
    kmin = min(kmin, key);
    kmax = max(kmax, key);
  }
#pragma unroll
  for (int o = 32; o > 0; o >>= 1) {
    kmin = min(kmin, (unsigned)__shfl_down((int)kmin, o, 64));
    kmax = max(kmax, (unsigned)__shfl_down((int)kmax, o, 64));
  }
  int wv = threadIdx.x >> 6;
  if ((threadIdx.x & 63) == 0) { smin[wv] = kmin; smax[wv] = kmax; }
  __syncthreads();
  if (threadIdx.x == 0) {
    kmin = min(min(smin[0], smin[1]), min(smin[2], smin[3]));
    kmax = max(max(smax[0], smax[1]), max(smax[2], smax[3]));
    mm[2 * blockIdx.x + 0] = kmin;
    mm[2 * blockIdx.x + 1] = kmax;
  }
}

// ---------------------------------------------------------------------------
// Main kernel: EIGHT LANES PER POINT, ONE fused J9 pass -- r12 RESTORED
// VERBATIM (measured optimum: 103.4 us, VGPR 84, VALUBusy 86%, occ 28%,
// zero spill).  All post-r12 variants regressed (r13-r16: 120/113/113/117).
// bits0-1 = hidden quarter Q, bit2 = family q.
//   q=0: dA=(k,0,0), dB=(k, k,0):  psi_x/xx/xxx, S2+/S3+, m+, p, p_x
//   q=1: dA=(0,k,0), dB=(k,-k,0):  psi_y/yy/yyy, S2-/S3-, m-, p_y
//   psi_xt = (m+ + m-)/2,  psi_yt = (m+ - m-)/2   [t-polarization]
// p output only needs {v, a1}: 2-float partial, not a full J9.
// Copy-back mid loop mandatory (r0/r4: unrolled ping-pong = GB-scale spill).
// ---------------------------------------------------------------------------
__global__ void __launch_bounds__(256, 2) pinn_main(
    const float* __restrict__ X,
    const float* W1, const float* b1, const float* W2, const float* b2,
    const float* W3, const float* b3, const float* W4, const float* b4,
    const float* W5, const float* b5, const float* W6, const float* b6,
    const float* W7, const float* b7, const float* W8, const float* b8,
    const float* lam1p, const float* lam2p, const unsigned* __restrict__ mm,
    float* __restrict__ out) {
  __shared__ float w[LDS_W_FLOATS];
  {
    const float* Wsrc[8] = {W1, W2, W3, W4, W5, W6, W7, W8};
    const float* bsrc[8] = {b1, b2, b3, b4, b5, b6, b7, b8};
    const int nwA[8]  = {9, 60, 400, 400, 400, 400, 400, 40};
    const int nbA[8]  = {3, 20, 20, 20, 20, 20, 20, 2};
    const int offW[8] = {0, 12, 92, 512, 932, 1352, 1772, 2192};
    const int offB[8] = {9, 72, 492, 912, 1332, 1752, 2172, 2232};
#pragma unroll
    for (int a = 0; a < 8; ++a) {
      for (int s = threadIdx.x; s < nwA[a]; s += 256) w[offW[a] + s] = Wsrc[a][s];
      for (int s = threadIdx.x; s < nbA[a]; s += 256) w[offB[a] + s] = bsrc[a][s];
    }
  }

  const int lane = threadIdx.x & 63;
  const int gid  = blockIdx.x * 256 + threadIdx.x;
  const int pt   = gid >> 3;           // point index (eight lanes per point)
  const int Q    = gid & 3;            // hidden quarter
  const int q    = (gid >> 2) & 1;     // family
  const int hb   = 5 * Q;
  const int hb1  = 5 * (Q ^ 1);
  const int hb2  = 5 * (Q ^ 2);
  const int hb3  = 5 * (Q ^ 3);

  // global min/max: lane l holds block-partial l, butterfly across the wave
  unsigned pmin = mm[2 * lane + 0];
  unsigned pmax = mm[2 * lane + 1];
#pragma unroll
  for (int o = 1; o < 64; o <<= 1) {
    pmin = min(pmin, (unsigned)__shfl_xor((int)pmin, o, 64));
    pmax = max(pmax, (unsigned)__shfl_xor((int)pmax, o, 64));
  }
  float lb = unflip(pmin);
  float ub = unflip(pmax);
  float kk = 2.0f / (ub - lb);

  float x = X[3 * pt], y = X[3 * pt + 1], tt = X[3 * pt + 2];
  float h0 = fmaf(kk, x - lb, -1.0f);
  float h1 = fmaf(kk, y - lb, -1.0f);
  float h2 = fmaf(kk, tt - lb, -1.0f);

  __syncthreads();  // weights staged

  // family-selected seeds (cndmask, no branch)
  float a0s = q ? 0.0f : kk, a1s = q ? kk : 0.0f;  // dA: x-dir / y-dir
  float b1s = q ? -kk : kk;                         // dB: (k,+-k,0)

  // ---- single fused network pass ----
  J9 A[5], B[5];
  {
    J9 T[3];
    {
      J9 I0 = J9::seed(0.f), I1 = J9::seed(0.f), I2 = J9::seed(0.f);
      I0.v = h0; I0.a1 = a0s; I0.b1 = kk;
      I1.v = h1; I1.a1 = a1s; I1.b1 = b1s;
      I2.v = h2; I2.t = kk;
#pragma unroll
      for (int j = 0; j < 3; ++j) {               // L1 3->3, duplicated
        J9 z = J9::seed(w[9 + j]);
        z.macc(w[0 * 3 + j], I0);
        z.macc(w[1 * 3 + j], I1);
        z.macc(w[2 * 3 + j], I2);
        T[j] = z.chain();
      }
    }
#pragma unroll
    for (int j = 0; j < 5; ++j) {                 // L2 3->20, split by quarter
      J9 z = J9::seed(w[72 + hb + j]);
#pragma unroll
      for (int i = 0; i < 3; ++i) z.macc(w[12 + i * 20 + hb + j], T[i]);
      A[j] = z.chain();
    }
  }
#pragma unroll 1
  for (int l = 0; l < 5; ++l) {                   // L3..L7, one hot body
    const float* Wl = w + 92 + l * 420;
    layer20_q(Wl, Wl + 400, hb, hb1, hb2, hb3, A, B);
#pragma unroll
    for (int jj = 0; jj < 5; ++jj) A[jj] = B[jj];
  }

  // L8 psi output: full 9-comp partial + intra-quad butterfly
  float rc1, rc2, rc3, s2, s3, rm;
  {
    J9 z = J9::seed(0.f);
#pragma unroll
    for (int ii = 0; ii < 5; ++ii) z.macc(w[2192 + (hb + ii) * 2 + 0], A[ii]);
    redsum<1>(z); redsum<2>(z);
    z.v += w[2232];
    J9 o = z.chain();
    rc1 = o.a1; rc2 = o.a2; rc3 = o.a3;
    s2 = o.b2; s3 = o.b3; rm = o.m;
  }
  // L8 p output: only {v, a1} needed -> 2-float partial
  float rpv, rpc;
  {
    float pv = 0.f, pa = 0.f;
#pragma unroll
    for (int ii = 0; ii < 5; ++ii) {
      float wt = w[2192 + (hb + ii) * 2 + 1];
      pv = fmaf(wt, A[ii].v,  pv);
      pa = fmaf(wt, A[ii].a1, pa);
    }
    pv += qperm<1>(pv); pa += qperm<1>(pa);
    pv += qperm<2>(pv); pa += qperm<2>(pa);
    pv += w[2233];
    float s = fast_tanh(pv);
    rpv = s;
    rpc = fmaf(-s, s, 1.0f) * pa;
  }

  // cross-family exchange (mask 4 -- crosses quads, keep __shfl_xor; cold)
  float psi_y   = __shfl_xor(rc1, 4, 64);
  float psi_yy  = __shfl_xor(rc2, 4, 64);
  float psi_yyy = __shfl_xor(rc3, 4, 64);
  float p_y     = __shfl_xor(rpc, 4, 64);
  float S2m     = __shfl_xor(s2, 4, 64);
  float S3m     = __shfl_xor(s3, 4, 64);
  float mB      = __shfl_xor(rm, 4, 64);   // m- (on q=0 lanes)

  if ((gid & 7) == 0) {
    float psi_x = rc1, psi_xx = rc2, psi_xxx = rc3;
    float p_val = rpv, p_x = rpc;
    float S2p = s2, S3p = s3;

    // polarization identities (spatial + t-polarization)
    float psi_xy  = 0.25f * (S2p - S2m);
    float psi_xxy = (S3p - S3m - 2.0f * psi_yyy) * (1.0f / 6.0f);
    float psi_xyy = (S3p + S3m - 2.0f * psi_xxx) * (1.0f / 6.0f);
    float psi_xt  = 0.5f * (rm + mB);
    float psi_yt  = 0.5f * (rm - mB);

    float u = psi_y, vv = -psi_x;
    float u_x = psi_xy,  u_y = psi_yy,  u_t = psi_yt;
    float v_x = -psi_xx, v_y = -psi_xy, v_t = -psi_xt;
    float u_xx = psi_xxy,  u_yy = psi_yyy;
    float v_xx = -psi_xxx, v_yy = -psi_xyy;

    float lam1 = lam1p[0], lam2 = lam2p[0];
    float f_u = u_t + lam1 * (u * u_x + vv * u_y) + p_x - lam2 * (u_xx + u_yy);
    float f_v = v_t + lam1 * (u * v_x + vv * v_y) + p_y - lam2 * (v_xx + v_yy);

    out[pt] = u;
    out[NPTS + pt] = vv;
    out[2 * NPTS + pt] = p_val;
    out[3 * NPTS + pt] = f_u;
    out[4 * NPTS + pt] = f_v;
  }
}

extern "C" void kernel_launch(void* const* d_in, const int* in_sizes, int n_in,
                              void* d_out, int out_size, void* d_ws, size_t ws_size,
                              hipStream_t stream) {
  (void)in_sizes; (void)n_in; (void)out_size; (void)ws_size;
  const float* X = (const float*)d_in[0];
  const float* W[8]; const float* B[8];
  for (int i = 0; i < 8; ++i) {
    W[i] = (const float*)d_in[1 + 2 * i];
    B[i] = (const float*)d_in[2 + 2 * i];
  }
  const float* lam1 = (const float*)d_in[17];
  const float* lam2 = (const float*)d_in[18];
  unsigned* mm = (unsigned*)d_ws;
  float* out = (float*)d_out;

  hipLaunchKernelGGL(mm_reduce, dim3(MM_BLOCKS), dim3(256), 0, stream, X, mm);
  hipLaunchKernelGGL(pinn_main, dim3(8 * NPTS / 256), dim3(256), 0, stream,
                     X, W[0], B[0], W[1], B[1], W[2], B[2], W[3], B[3],
                     W[4], B[4], W[5], B[5], W[6], B[6], W[7], B[7],
                     lam1, lam2, mm, out);
}